// Round 3
// baseline (206.290 us; speedup 1.0000x reference)
//
#include <hip/hip_runtime.h>
#include <hip/hip_bf16.h>
#include <math.h>

// (B,P,V,F,H) = (32,512,32,16,64). One wave = one bp; wave loops over 8 bp.
// Weights held in registers as MFMA B-frags for the whole kernel.
// M = 32 v-rows (2 m-tiles), N = 64 h-cols (4 n-tiles), K = 128 (4 k-steps).
// MFMA 16x16x32 bf16: A[m=lane&15][k=quad*8+j], B[k=quad*8+j][n=lane&15],
//                     D[row=quad*4+reg][col=lane&15].
// LDS per wave: x-buffer 32 rows x 72 shorts (out half only, 64+8 pad),
// ping-pong x2, plus 64-entry bf16 pool array x2. No __syncthreads anywhere
// (wave-private buffers; DS pipe is in-order within a wave).
namespace {
constexpr int kXS = 72;          // shorts per x-row
constexpr float kSlope = 0.01f;

typedef short bf16x8 __attribute__((ext_vector_type(8)));
typedef float f32x4  __attribute__((ext_vector_type(4)));

__device__ __forceinline__ float lrelu(float x) { return fmaxf(x, kSlope * x); }

__device__ __forceinline__ short2 cvt2bf(float a, float b) {
    union { __hip_bfloat162 h; short2 s; } u;
    u.h = __float22bfloat162_rn(float2{a, b});
    return u.s;
}
__device__ __forceinline__ short cvt1bf(float a) {
    union { __hip_bfloat16 h; short s; } u;
    u.h = __float2bfloat16(a);
    return u.s;
}
__device__ __forceinline__ bf16x8 pack8(float4 f0, float4 f1) {
    short2 a0 = cvt2bf(f0.x, f0.y), a1 = cvt2bf(f0.z, f0.w);
    short2 a2 = cvt2bf(f1.x, f1.y), a3 = cvt2bf(f1.z, f1.w);
    bf16x8 v;
    v[0]=a0.x; v[1]=a0.y; v[2]=a1.x; v[3]=a1.y;
    v[4]=a2.x; v[5]=a2.y; v[6]=a3.x; v[7]=a3.y;
    return v;
}

__global__ __launch_bounds__(256, 2) void fused_mlp_regW(
    const float* __restrict__ X, const int* __restrict__ M,
    const float* __restrict__ W1, const float* __restrict__ B1,
    const float* __restrict__ W2, const float* __restrict__ B2,
    const float* __restrict__ W3, const float* __restrict__ B3,
    float* __restrict__ OUT)
{
    __shared__ __align__(16) short sX[4][2][32 * kXS];  // 36864 B
    __shared__ __align__(16) short sP[4][2][64];        //  1024 B

    const int t = threadIdx.x;
    const int w = t >> 6, l = t & 63, c = l & 15, q = l >> 4;

    // ---- persistent weight B-frags (global -> registers, once per wave) ----
    bf16x8 w1f[4], w2f[4][4], w3f[4][4];
    #pragma unroll
    for (int nt = 0; nt < 4; ++nt) {
        {
            bf16x8 v = {};
            if (q < 2) {
                const float4* p = (const float4*)(W1 + (16*nt + c) * 16 + q*8);
                v = pack8(p[0], p[1]);
            }
            w1f[nt] = v;
        }
        #pragma unroll
        for (int ks = 0; ks < 4; ++ks) {
            const float4* p2 = (const float4*)(W2 + (16*nt + c) * 128 + ks*32 + q*8);
            w2f[nt][ks] = pack8(p2[0], p2[1]);
            const float4* p3 = (const float4*)(W3 + (16*nt + c) * 128 + ks*32 + q*8);
            w3f[nt][ks] = pack8(p3[0], p3[1]);
        }
    }
    float bias1[4], bias2[4], bias3[4];
    #pragma unroll
    for (int nt = 0; nt < 4; ++nt) {
        bias1[nt] = B1[16*nt + c];
        bias2[nt] = B2[16*nt + c];
        bias3[nt] = B3[16*nt + c];
    }

    short* xb2 = &sX[w][0][0]; short* pl2 = &sP[w][0][0];
    short* xb3 = &sX[w][1][0]; short* pl3 = &sP[w][1][0];

    size_t bp = (size_t)blockIdx.x * 4 + w;
    float4 xr[2][2];
    int4 mr0, mr1;
    {   // prefetch iteration 0
        if (q < 2) {
            #pragma unroll
            for (int mt = 0; mt < 2; ++mt) {
                const float4* p = (const float4*)(X + (bp*32 + 16*mt + c) * 16 + q*8);
                xr[mt][0] = p[0]; xr[mt][1] = p[1];
            }
        }
        const int4* Mp = (const int4*)(M + bp * 32);
        mr0 = Mp[q]; mr1 = Mp[4 + q];
    }

    f32x4 acc[2][4];

    #pragma unroll 1
    for (int it = 0; it < 8; ++it) {
        const size_t bp_cur = bp;
        bf16x8 a1f[2];
        {
            bf16x8 z = {};
            a1f[0] = (q < 2) ? pack8(xr[0][0], xr[0][1]) : z;
            a1f[1] = (q < 2) ? pack8(xr[1][0], xr[1][1]) : z;
        }
        const unsigned mbits =
            (mr0.x ? 1u : 0u)  | (mr0.y ? 2u : 0u)  | (mr0.z ? 4u : 0u)  | (mr0.w ? 8u : 0u) |
            (mr1.x ? 16u : 0u) | (mr1.y ? 32u : 0u) | (mr1.z ? 64u : 0u) | (mr1.w ? 128u : 0u);
        const bool anyv = __any(mbits != 0);

        if (it < 7) {   // software-pipelined prefetch of next bp
            bp += 2048;
            if (q < 2) {
                #pragma unroll
                for (int mt = 0; mt < 2; ++mt) {
                    const float4* p = (const float4*)(X + (bp*32 + 16*mt + c) * 16 + q*8);
                    xr[mt][0] = p[0]; xr[mt][1] = p[1];
                }
            }
            const int4* Mp = (const int4*)(M + bp * 32);
            mr0 = Mp[q]; mr1 = Mp[4 + q];
        }

        // ---- layer 1 (K=16 zero-padded to 32) ----
        #pragma unroll
        for (int mt = 0; mt < 2; ++mt)
            #pragma unroll
            for (int nt = 0; nt < 4; ++nt) {
                f32x4 cc = { bias1[nt], bias1[nt], bias1[nt], bias1[nt] };
                acc[mt][nt] = __builtin_amdgcn_mfma_f32_16x16x32_bf16(a1f[mt], w1f[nt], cc, 0, 0, 0);
            }

        // ---- epilogue: lrelu/mask, paired b32 out-writes, pool -> bf16 array ----
        auto epilogue = [&](short* xb, short* pl) {
            float pool[4];
            #pragma unroll
            for (int nt = 0; nt < 4; ++nt) {
                float pv = -INFINITY;
                #pragma unroll
                for (int mt = 0; mt < 2; ++mt) {
                    short2 pk[4];
                    #pragma unroll
                    for (int r = 0; r < 4; ++r) {
                        float y = lrelu(acc[mt][nt][r]);
                        bool mk = (mbits >> (mt*4 + r)) & 1;
                        float o = mk ? y : 0.f;
                        pv = mk ? fmaxf(pv, y) : pv;
                        float g = __shfl_xor(o, 1);
                        pk[r] = (c & 1) ? cvt2bf(g, o) : cvt2bf(o, g);
                    }
                    short2 wa = (c & 1) ? pk[2] : pk[0];
                    short2 wb = (c & 1) ? pk[3] : pk[1];
                    int rb   = 16*mt + 4*q + 2*(c & 1);
                    int colb = 16*nt + (c & ~1);
                    *(short2*)&xb[ rb      * kXS + colb] = wa;
                    *(short2*)&xb[(rb + 1) * kXS + colb] = wb;
                }
                pv = fmaxf(pv, __shfl_xor(pv, 16));
                pv = fmaxf(pv, __shfl_xor(pv, 32));
                pool[nt] = anyv ? pv : 0.f;
            }
            float ps = (q & 2) ? ((q & 1) ? pool[3] : pool[2])
                               : ((q & 1) ? pool[1] : pool[0]);
            pl[16*q + c] = cvt1bf(ps);
        };

        // ---- K=128 layer from LDS x-buffer + pool array, weights in regs ----
        auto layer = [&](const short* xb, const short* pl,
                         const bf16x8 (&wf)[4][4], const float (&bias)[4]) {
            #pragma unroll
            for (int mt = 0; mt < 2; ++mt)
                #pragma unroll
                for (int nt = 0; nt < 4; ++nt)
                    acc[mt][nt] = f32x4{ bias[nt], bias[nt], bias[nt], bias[nt] };
            #pragma unroll
            for (int ks = 0; ks < 4; ++ks) {
                bf16x8 a[2];
                if (ks < 2) {
                    a[0] = *(const bf16x8*)&xb[(     c) * kXS + ks*32 + q*8];
                    a[1] = *(const bf16x8*)&xb[(16 + c) * kXS + ks*32 + q*8];
                } else {
                    bf16x8 ar = *(const bf16x8*)&pl[(ks - 2)*32 + q*8];  // quad-broadcast
                    a[0] = ar; a[1] = ar;
                }
                #pragma unroll
                for (int mt = 0; mt < 2; ++mt)
                    #pragma unroll
                    for (int nt = 0; nt < 4; ++nt)
                        acc[mt][nt] = __builtin_amdgcn_mfma_f32_16x16x32_bf16(a[mt], wf[nt][ks], acc[mt][nt], 0, 0, 0);
            }
        };

        epilogue(xb2, pl2);
        layer(xb2, pl2, w2f, bias2);
        epilogue(xb3, pl3);
        layer(xb3, pl3, w3f, bias3);

        // ---- layer-3 pool == final output ----
        {
            float pool[4];
            #pragma unroll
            for (int nt = 0; nt < 4; ++nt) {
                float pv = -INFINITY;
                #pragma unroll
                for (int mt = 0; mt < 2; ++mt)
                    #pragma unroll
                    for (int r = 0; r < 4; ++r) {
                        bool mk = (mbits >> (mt*4 + r)) & 1;
                        float y = lrelu(acc[mt][nt][r]);
                        pv = mk ? fmaxf(pv, y) : pv;
                    }
                pv = fmaxf(pv, __shfl_xor(pv, 16));
                pv = fmaxf(pv, __shfl_xor(pv, 32));
                pool[nt] = anyv ? pv : 0.f;
            }
            float ps = (q & 2) ? ((q & 1) ? pool[3] : pool[2])
                               : ((q & 1) ? pool[1] : pool[0]);
            OUT[bp_cur * 64 + 16*q + c] = ps;
        }
    }
}
} // namespace

extern "C" void kernel_launch(void* const* d_in, const int* in_sizes, int n_in,
                              void* d_out, int out_size, void* d_ws, size_t ws_size,
                              hipStream_t stream) {
    (void)in_sizes; (void)n_in; (void)d_ws; (void)ws_size; (void)out_size;
    const float* X  = (const float*)d_in[0];
    const int*   M  = (const int*)d_in[1];
    const float* W1 = (const float*)d_in[2];
    const float* B1 = (const float*)d_in[3];
    const float* W2 = (const float*)d_in[4];
    const float* B2 = (const float*)d_in[5];
    const float* W3 = (const float*)d_in[6];
    const float* B3 = (const float*)d_in[7];
    float* OUT = (float*)d_out;

    // 512 blocks x 4 waves = 2048 waves; each wave loops over 8 bp (16384 total)
    fused_mlp_regW<<<512, 256, 0, stream>>>(X, M, W1, B1, W2, B2, W3, B3, OUT);
}

// Round 4
// 177.231 us; speedup vs baseline: 1.1640x; 1.1640x over previous
//
#include <hip/hip_runtime.h>
#include <hip/hip_bf16.h>
#include <math.h>

// (B,P,V,F,H) = (32,512,32,16,64). One BLOCK = one wave (64 threads) = one bp
// at a time; each wave loops over 8 bp (grid 2048). Weights held in registers
// as MFMA B-frags for the whole kernel — __launch_bounds__(64,1) gives the
// allocator up to 512 VGPRs so the ~220-reg working set cannot spill (round-3
// failure mode: launch_bounds(256,2) capped at 128 VGPR -> 80 MB scratch).
// M = 32 v-rows (2 m-tiles), N = 64 h-cols (4 n-tiles), K = 128 (4 k-steps).
// MFMA 16x16x32 bf16: A[m=lane&15][k=quad*8+j], B[k=quad*8+j][n=lane&15],
//                     D[row=quad*4+reg][col=lane&15].
// LDS per block: x-buffer 32 rows x 72 shorts (out half only), ping-pong x2,
// plus 64-entry bf16 pool array x2 (rep half never materialized). No
// __syncthreads anywhere (single wave; DS pipe is in-order within a wave).
namespace {
constexpr int kXS = 72;          // shorts per x-row
constexpr float kSlope = 0.01f;

typedef short bf16x8 __attribute__((ext_vector_type(8)));
typedef float f32x4  __attribute__((ext_vector_type(4)));

__device__ __forceinline__ float lrelu(float x) { return fmaxf(x, kSlope * x); }

__device__ __forceinline__ short2 cvt2bf(float a, float b) {
    union { __hip_bfloat162 h; short2 s; } u;
    u.h = __float22bfloat162_rn(float2{a, b});
    return u.s;
}
__device__ __forceinline__ short cvt1bf(float a) {
    union { __hip_bfloat16 h; short s; } u;
    u.h = __float2bfloat16(a);
    return u.s;
}
__device__ __forceinline__ bf16x8 pack8(float4 f0, float4 f1) {
    short2 a0 = cvt2bf(f0.x, f0.y), a1 = cvt2bf(f0.z, f0.w);
    short2 a2 = cvt2bf(f1.x, f1.y), a3 = cvt2bf(f1.z, f1.w);
    bf16x8 v;
    v[0]=a0.x; v[1]=a0.y; v[2]=a1.x; v[3]=a1.y;
    v[4]=a2.x; v[5]=a2.y; v[6]=a3.x; v[7]=a3.y;
    return v;
}

__global__ __launch_bounds__(64, 1) void fused_mlp_regW(
    const float* __restrict__ X, const int* __restrict__ M,
    const float* __restrict__ W1, const float* __restrict__ B1,
    const float* __restrict__ W2, const float* __restrict__ B2,
    const float* __restrict__ W3, const float* __restrict__ B3,
    float* __restrict__ OUT)
{
    __shared__ __align__(16) short sX[2][32 * kXS];  // 9216 B
    __shared__ __align__(16) short sP[2][64];        //  256 B

    const int l = threadIdx.x;
    const int c = l & 15, q = l >> 4;

    // ---- persistent weight B-frags (global -> registers, once per wave) ----
    bf16x8 w1f[4], w2f[4][4], w3f[4][4];
    #pragma unroll
    for (int nt = 0; nt < 4; ++nt) {
        {
            bf16x8 v = {};
            if (q < 2) {
                const float4* p = (const float4*)(W1 + (16*nt + c) * 16 + q*8);
                v = pack8(p[0], p[1]);
            }
            w1f[nt] = v;
        }
        #pragma unroll
        for (int ks = 0; ks < 4; ++ks) {
            const float4* p2 = (const float4*)(W2 + (16*nt + c) * 128 + ks*32 + q*8);
            w2f[nt][ks] = pack8(p2[0], p2[1]);
            const float4* p3 = (const float4*)(W3 + (16*nt + c) * 128 + ks*32 + q*8);
            w3f[nt][ks] = pack8(p3[0], p3[1]);
        }
    }
    float bias1[4], bias2[4], bias3[4];
    #pragma unroll
    for (int nt = 0; nt < 4; ++nt) {
        bias1[nt] = B1[16*nt + c];
        bias2[nt] = B2[16*nt + c];
        bias3[nt] = B3[16*nt + c];
    }

    short* xb2 = &sX[0][0]; short* pl2 = &sP[0][0];
    short* xb3 = &sX[1][0]; short* pl3 = &sP[1][0];

    size_t bp = (size_t)blockIdx.x;
    float4 xr[2][2];
    int4 mr0, mr1;
    {   // prefetch iteration 0
        if (q < 2) {
            #pragma unroll
            for (int mt = 0; mt < 2; ++mt) {
                const float4* p = (const float4*)(X + (bp*32 + 16*mt + c) * 16 + q*8);
                xr[mt][0] = p[0]; xr[mt][1] = p[1];
            }
        }
        const int4* Mp = (const int4*)(M + bp * 32);
        mr0 = Mp[q]; mr1 = Mp[4 + q];
    }

    f32x4 acc[2][4];

    #pragma unroll 1
    for (int it = 0; it < 8; ++it) {
        const size_t bp_cur = bp;
        bf16x8 a1f[2];
        {
            bf16x8 z = {};
            a1f[0] = (q < 2) ? pack8(xr[0][0], xr[0][1]) : z;
            a1f[1] = (q < 2) ? pack8(xr[1][0], xr[1][1]) : z;
        }
        const unsigned mbits =
            (mr0.x ? 1u : 0u)  | (mr0.y ? 2u : 0u)  | (mr0.z ? 4u : 0u)  | (mr0.w ? 8u : 0u) |
            (mr1.x ? 16u : 0u) | (mr1.y ? 32u : 0u) | (mr1.z ? 64u : 0u) | (mr1.w ? 128u : 0u);
        const bool anyv = __any(mbits != 0);

        if (it < 7) {   // software-pipelined prefetch of next bp
            bp += 2048;
            if (q < 2) {
                #pragma unroll
                for (int mt = 0; mt < 2; ++mt) {
                    const float4* p = (const float4*)(X + (bp*32 + 16*mt + c) * 16 + q*8);
                    xr[mt][0] = p[0]; xr[mt][1] = p[1];
                }
            }
            const int4* Mp = (const int4*)(M + bp * 32);
            mr0 = Mp[q]; mr1 = Mp[4 + q];
        }

        // ---- layer 1 (K=16 zero-padded to 32) ----
        #pragma unroll
        for (int mt = 0; mt < 2; ++mt)
            #pragma unroll
            for (int nt = 0; nt < 4; ++nt) {
                f32x4 cc = { bias1[nt], bias1[nt], bias1[nt], bias1[nt] };
                acc[mt][nt] = __builtin_amdgcn_mfma_f32_16x16x32_bf16(a1f[mt], w1f[nt], cc, 0, 0, 0);
            }

        // ---- epilogue: lrelu/mask, paired b32 out-writes, pool -> bf16 array ----
        auto epilogue = [&](short* xb, short* pl) {
            float pool[4];
            #pragma unroll
            for (int nt = 0; nt < 4; ++nt) {
                float pv = -INFINITY;
                #pragma unroll
                for (int mt = 0; mt < 2; ++mt) {
                    short2 pk[4];
                    #pragma unroll
                    for (int r = 0; r < 4; ++r) {
                        float y = lrelu(acc[mt][nt][r]);
                        bool mk = (mbits >> (mt*4 + r)) & 1;
                        float o = mk ? y : 0.f;
                        pv = mk ? fmaxf(pv, y) : pv;
                        float g = __shfl_xor(o, 1);
                        pk[r] = (c & 1) ? cvt2bf(g, o) : cvt2bf(o, g);
                    }
                    short2 wa = (c & 1) ? pk[2] : pk[0];
                    short2 wb = (c & 1) ? pk[3] : pk[1];
                    int rb   = 16*mt + 4*q + 2*(c & 1);
                    int colb = 16*nt + (c & ~1);
                    *(short2*)&xb[ rb      * kXS + colb] = wa;
                    *(short2*)&xb[(rb + 1) * kXS + colb] = wb;
                }
                pv = fmaxf(pv, __shfl_xor(pv, 16));
                pv = fmaxf(pv, __shfl_xor(pv, 32));
                pool[nt] = anyv ? pv : 0.f;
            }
            float ps = (q & 2) ? ((q & 1) ? pool[3] : pool[2])
                               : ((q & 1) ? pool[1] : pool[0]);
            pl[16*q + c] = cvt1bf(ps);
        };

        // ---- K=128 layer from LDS x-buffer + pool array, weights in regs ----
        auto layer = [&](const short* xb, const short* pl,
                         const bf16x8 (&wf)[4][4], const float (&bias)[4]) {
            #pragma unroll
            for (int mt = 0; mt < 2; ++mt)
                #pragma unroll
                for (int nt = 0; nt < 4; ++nt)
                    acc[mt][nt] = f32x4{ bias[nt], bias[nt], bias[nt], bias[nt] };
            #pragma unroll
            for (int ks = 0; ks < 4; ++ks) {
                bf16x8 a[2];
                if (ks < 2) {
                    a[0] = *(const bf16x8*)&xb[(     c) * kXS + ks*32 + q*8];
                    a[1] = *(const bf16x8*)&xb[(16 + c) * kXS + ks*32 + q*8];
                } else {
                    bf16x8 ar = *(const bf16x8*)&pl[(ks - 2)*32 + q*8];  // quad-broadcast
                    a[0] = ar; a[1] = ar;
                }
                #pragma unroll
                for (int mt = 0; mt < 2; ++mt)
                    #pragma unroll
                    for (int nt = 0; nt < 4; ++nt)
                        acc[mt][nt] = __builtin_amdgcn_mfma_f32_16x16x32_bf16(a[mt], wf[nt][ks], acc[mt][nt], 0, 0, 0);
            }
        };

        epilogue(xb2, pl2);
        layer(xb2, pl2, w2f, bias2);
        epilogue(xb3, pl3);
        layer(xb3, pl3, w3f, bias3);

        // ---- layer-3 pool == final output ----
        {
            float pool[4];
            #pragma unroll
            for (int nt = 0; nt < 4; ++nt) {
                float pv = -INFINITY;
                #pragma unroll
                for (int mt = 0; mt < 2; ++mt)
                    #pragma unroll
                    for (int r = 0; r < 4; ++r) {
                        bool mk = (mbits >> (mt*4 + r)) & 1;
                        float y = lrelu(acc[mt][nt][r]);
                        pv = mk ? fmaxf(pv, y) : pv;
                    }
                pv = fmaxf(pv, __shfl_xor(pv, 16));
                pv = fmaxf(pv, __shfl_xor(pv, 32));
                pool[nt] = anyv ? pv : 0.f;
            }
            float ps = (q & 2) ? ((q & 1) ? pool[3] : pool[2])
                               : ((q & 1) ? pool[1] : pool[0]);
            OUT[bp_cur * 64 + 16*q + c] = ps;
        }
    }
}
} // namespace

extern "C" void kernel_launch(void* const* d_in, const int* in_sizes, int n_in,
                              void* d_out, int out_size, void* d_ws, size_t ws_size,
                              hipStream_t stream) {
    (void)in_sizes; (void)n_in; (void)d_ws; (void)ws_size; (void)out_size;
    const float* X  = (const float*)d_in[0];
    const int*   M  = (const int*)d_in[1];
    const float* W1 = (const float*)d_in[2];
    const float* B1 = (const float*)d_in[3];
    const float* W2 = (const float*)d_in[4];
    const float* B2 = (const float*)d_in[5];
    const float* W3 = (const float*)d_in[6];
    const float* B3 = (const float*)d_in[7];
    float* OUT = (float*)d_out;

    // 2048 single-wave blocks; each wave loops over 8 bp (16384 total)
    fused_mlp_regW<<<2048, 64, 0, stream>>>(X, M, W1, B1, W2, B2, W3, B3, OUT);
}

// Round 5
// 118.301 us; speedup vs baseline: 1.7438x; 1.4981x over previous
//
#include <hip/hip_runtime.h>
#include <math.h>

// (B,P,V,F,H) = (32,512,32,16,64). Round 5: one wave = one bp, no bp loop.
// Weights pre-packed by a tiny pre-pass kernel into bf16 MFMA B-fragment
// order in d_ws (36 frags x 64 lanes x 16 B = 36 KB, L1/L2-resident); the
// main kernel fetches each frag as one global_load_dwordx4 on the VMEM pipe,
// keeping the DS pipe for activations and VGPRs low enough for 4 waves/SIMD
// (round-4 failure: register-resident W -> 2 waves/SIMD -> latency-bound).
// MFMA 16x16x32 bf16: A[m=lane&15][k=quad*8+j], B[k=quad*8+j][n=lane&15],
//                     D[row=quad*4+reg][col=lane&15]  (verified rounds 2-4).
// LDS per wave: x-buffer 32 x 72 shorts (out half only) x2 + 64-short pool
// array x2; rep half never materialized. No __syncthreads (wave-private).
namespace {
constexpr int kXS = 72;
constexpr float kSlope = 0.01f;

typedef short bf16x8 __attribute__((ext_vector_type(8)));
typedef float f32x4  __attribute__((ext_vector_type(4)));

__device__ __forceinline__ float lrelu(float x) { return fmaxf(x, kSlope * x); }

// 3-instruction round-to-nearest-even f32->bf16 (inputs are finite here;
// avoids the branchy NaN-handling __float2bfloat16 intrinsic).
__device__ __forceinline__ unsigned short bfrne(float a) {
    union { float f; unsigned u; } v; v.f = a;
    return (unsigned short)((v.u + 0x7FFFu + ((v.u >> 16) & 1u)) >> 16);
}

// ---- pre-pass: pack W1/W2/W3 as bf16 MFMA B-frags into d_ws ----
// frag f: 0..3 = W1 (nt=f, K=16 zero-padded); 4..19 = W2 (nt=(f-4)>>2,
// ks=(f-4)&3); 20..35 = W3. Lane l of frag f lives at ws[f*512 + l*8 ..+7].
__global__ void prep_weights(const float* __restrict__ W1,
                             const float* __restrict__ W2,
                             const float* __restrict__ W3,
                             unsigned short* __restrict__ ws)
{
    int t = blockIdx.x * blockDim.x + threadIdx.x;
    if (t >= 36 * 64) return;
    int f = t >> 6, l = t & 63, c = l & 15, q = l >> 4;
    unsigned short v[8] = {0, 0, 0, 0, 0, 0, 0, 0};
    const float* src = nullptr; int row = 0, k0 = 0, K = 0;
    if (f < 4) {
        if (q < 2) { src = W1; row = 16 * f + c; k0 = q * 8; K = 16; }
    } else if (f < 20) {
        int g = f - 4;  src = W2; row = 16 * (g >> 2) + c; k0 = (g & 3) * 32 + q * 8; K = 128;
    } else {
        int g = f - 20; src = W3; row = 16 * (g >> 2) + c; k0 = (g & 3) * 32 + q * 8; K = 128;
    }
    if (src) {
        #pragma unroll
        for (int j = 0; j < 8; ++j) v[j] = bfrne(src[row * K + k0 + j]);
    }
    unsigned short* dst = ws + (size_t)f * 512 + l * 8;
    *(ushort4*)(dst)     = make_ushort4(v[0], v[1], v[2], v[3]);
    *(ushort4*)(dst + 4) = make_ushort4(v[4], v[5], v[6], v[7]);
}

__global__ __launch_bounds__(256, 4) void fused_mlp_v5(
    const float* __restrict__ X, const int* __restrict__ M,
    const unsigned short* __restrict__ WF,
    const float* __restrict__ B1, const float* __restrict__ B2,
    const float* __restrict__ B3, float* __restrict__ OUT)
{
    __shared__ __align__(16) short sX[4][2][32 * kXS];  // 36864 B
    __shared__ __align__(16) short sP[4][2][64];        //  1024 B

    const int t = threadIdx.x, w = t >> 6, l = t & 63, c = l & 15, q = l >> 4;
    const size_t bp = (size_t)blockIdx.x * 4 + w;

    short* xb2 = &sX[w][0][0]; short* pl2 = &sP[w][0][0];
    short* xb3 = &sX[w][1][0]; short* pl3 = &sP[w][1][0];

    // ---- inputs for this bp ----
    float4 xr[2][2];
    if (q < 2) {
        #pragma unroll
        for (int mt = 0; mt < 2; ++mt) {
            const float4* p = (const float4*)(X + (bp * 32 + 16 * mt + c) * 16 + q * 8);
            xr[mt][0] = p[0]; xr[mt][1] = p[1];
        }
    }
    const int4* Mp = (const int4*)(M + bp * 32);
    const int4 mr0 = Mp[q], mr1 = Mp[4 + q];
    const unsigned mbits =
        (mr0.x ? 1u : 0u)  | (mr0.y ? 2u : 0u)  | (mr0.z ? 4u : 0u)  | (mr0.w ? 8u : 0u) |
        (mr1.x ? 16u : 0u) | (mr1.y ? 32u : 0u) | (mr1.z ? 64u : 0u) | (mr1.w ? 128u : 0u);
    const bool anyv = __any(mbits != 0);

    float bias1[4], bias2[4], bias3[4];
    #pragma unroll
    for (int nt = 0; nt < 4; ++nt) {
        bias1[nt] = B1[16 * nt + c];
        bias2[nt] = B2[16 * nt + c];
        bias3[nt] = B3[16 * nt + c];
    }

    f32x4 acc[2][4];

    // ---- layer 1 (K=16 zero-padded to 32); W1 frags from WF ----
    {
        bf16x8 a1f[2];
        #pragma unroll
        for (int mt = 0; mt < 2; ++mt) {
            bf16x8 v = {};
            if (q < 2) {
                float4 f0 = xr[mt][0], f1 = xr[mt][1];
                v[0] = (short)bfrne(f0.x); v[1] = (short)bfrne(f0.y);
                v[2] = (short)bfrne(f0.z); v[3] = (short)bfrne(f0.w);
                v[4] = (short)bfrne(f1.x); v[5] = (short)bfrne(f1.y);
                v[6] = (short)bfrne(f1.z); v[7] = (short)bfrne(f1.w);
            }
            a1f[mt] = v;
        }
        #pragma unroll
        for (int nt = 0; nt < 4; ++nt) {
            bf16x8 wf = *(const bf16x8*)(WF + (size_t)nt * 512 + l * 8);
            f32x4 c0 = { bias1[nt], bias1[nt], bias1[nt], bias1[nt] };
            acc[0][nt] = __builtin_amdgcn_mfma_f32_16x16x32_bf16(a1f[0], wf, c0, 0, 0, 0);
            acc[1][nt] = __builtin_amdgcn_mfma_f32_16x16x32_bf16(a1f[1], wf, c0, 0, 0, 0);
        }
    }

    // ---- epilogue: lrelu/mask, direct b16 writes (imm offsets), pool array ----
    auto epilogue = [&](short* xb, short* pl) {
        float pool[4];
        #pragma unroll
        for (int nt = 0; nt < 4; ++nt) {
            float pv = -INFINITY;
            #pragma unroll
            for (int mt = 0; mt < 2; ++mt) {
                short* base = &xb[(16 * mt + 4 * q) * kXS + 16 * nt + c];
                #pragma unroll
                for (int r = 0; r < 4; ++r) {
                    float y = lrelu(acc[mt][nt][r]);
                    bool mk = (mbits >> (mt * 4 + r)) & 1;
                    float o = mk ? y : 0.f;
                    pv = mk ? fmaxf(pv, y) : pv;
                    base[r * kXS] = (short)bfrne(o);
                }
            }
            pv = fmaxf(pv, __shfl_xor(pv, 16));
            pv = fmaxf(pv, __shfl_xor(pv, 32));
            pool[nt] = anyv ? pv : 0.f;
        }
        float ps = (q & 2) ? ((q & 1) ? pool[3] : pool[2])
                           : ((q & 1) ? pool[1] : pool[0]);
        pl[16 * q + c] = (short)bfrne(ps);
    };

    // ---- K=128 layer: A-frags from LDS, W-frags streamed from WF (VMEM) ----
    auto layerK = [&](const short* xb, const short* pl, int fb, const float (&bias)[4]) {
        bf16x8 a00 = *(const bf16x8*)&xb[(     c) * kXS      + q * 8];
        bf16x8 a01 = *(const bf16x8*)&xb[(16 + c) * kXS      + q * 8];
        bf16x8 a10 = *(const bf16x8*)&xb[(     c) * kXS + 32 + q * 8];
        bf16x8 a11 = *(const bf16x8*)&xb[(16 + c) * kXS + 32 + q * 8];
        bf16x8 ap0 = *(const bf16x8*)&pl[q * 8];        // quad-broadcast
        bf16x8 ap1 = *(const bf16x8*)&pl[32 + q * 8];
        #pragma unroll
        for (int nt = 0; nt < 4; ++nt) {
            acc[0][nt] = f32x4{ bias[nt], bias[nt], bias[nt], bias[nt] };
            acc[1][nt] = acc[0][nt];
        }
        #pragma unroll
        for (int ks = 0; ks < 4; ++ks) {
            bf16x8 am0 = (ks == 0) ? a00 : (ks == 1) ? a10 : (ks == 2) ? ap0 : ap1;
            bf16x8 am1 = (ks == 0) ? a01 : (ks == 1) ? a11 : (ks == 2) ? ap0 : ap1;
            #pragma unroll
            for (int nt = 0; nt < 4; ++nt) {
                bf16x8 wf = *(const bf16x8*)(WF + ((size_t)(fb + nt * 4 + ks)) * 512 + l * 8);
                acc[0][nt] = __builtin_amdgcn_mfma_f32_16x16x32_bf16(am0, wf, acc[0][nt], 0, 0, 0);
                acc[1][nt] = __builtin_amdgcn_mfma_f32_16x16x32_bf16(am1, wf, acc[1][nt], 0, 0, 0);
            }
        }
    };

    epilogue(xb2, pl2);
    layerK(xb2, pl2, 4, bias2);
    epilogue(xb3, pl3);
    layerK(xb3, pl3, 20, bias3);

    // ---- layer-3 pool == final output ----
    {
        float pool[4];
        #pragma unroll
        for (int nt = 0; nt < 4; ++nt) {
            float pv = -INFINITY;
            #pragma unroll
            for (int mt = 0; mt < 2; ++mt)
                #pragma unroll
                for (int r = 0; r < 4; ++r) {
                    bool mk = (mbits >> (mt * 4 + r)) & 1;
                    float y = lrelu(acc[mt][nt][r]);
                    pv = mk ? fmaxf(pv, y) : pv;
                }
            pv = fmaxf(pv, __shfl_xor(pv, 16));
            pv = fmaxf(pv, __shfl_xor(pv, 32));
            pool[nt] = anyv ? pv : 0.f;
        }
        float ps = (q & 2) ? ((q & 1) ? pool[3] : pool[2])
                           : ((q & 1) ? pool[1] : pool[0]);
        OUT[bp * 64 + 16 * q + c] = ps;
    }
}
} // namespace

extern "C" void kernel_launch(void* const* d_in, const int* in_sizes, int n_in,
                              void* d_out, int out_size, void* d_ws, size_t ws_size,
                              hipStream_t stream) {
    (void)in_sizes; (void)n_in; (void)ws_size; (void)out_size;
    const float* X  = (const float*)d_in[0];
    const int*   M  = (const int*)d_in[1];
    const float* W1 = (const float*)d_in[2];
    const float* B1 = (const float*)d_in[3];
    const float* W2 = (const float*)d_in[4];
    const float* B2 = (const float*)d_in[5];
    const float* W3 = (const float*)d_in[6];
    const float* B3 = (const float*)d_in[7];
    float* OUT = (float*)d_out;
    unsigned short* WF = (unsigned short*)d_ws;   // needs 36 KB of scratch

    prep_weights<<<(36 * 64 + 255) / 256, 256, 0, stream>>>(W1, W2, W3, WF);
    // 4096 blocks x 4 waves = 16384 waves; one bp per wave
    fused_mlp_v5<<<4096, 256, 0, stream>>>(X, M, WF, B1, B2, B3, OUT);
}